// Round 3
// baseline (149.744 us; speedup 1.0000x reference)
//
#include <hip/hip_runtime.h>
#include <hip/hip_bf16.h>
#include <math.h>
#include <stdint.h>

// ---------------------------------------------------------------------------
// MultiSimilarityLoss on MI355X.
//   x: [B=4096, D=1024] fp32 (L2-normalized rows), labels: [B] int32
//   out: scalar fp32 = mean over rows of mined multi-similarity loss
// Pipeline:
//   K1: x fp32 -> bf16 (ws)
//   K2: sim = X@X^T, SYMMETRIC: only upper-triangle 128x128 tiles computed,
//       each result mirrored to the lower triangle. (R2: full grid was
//       staging-BW bound at 537 MB logical L2 reads; symmetry halves it.)
//   K3: per-row mining + loss -> rowbuf[i]; 4 rows/block, single pass over
//       sim with reg-stashed values (R2 did two global passes).
//   K4: reduce rowbuf -> out[0]
// ---------------------------------------------------------------------------

#define THRESH    0.5f
#define MARGIN    0.1f
#define SCALE_POS 2.0f
#define SCALE_NEG 40.0f
#define POS_CAP   (1.0f - 1e-5f)

typedef __bf16 bf16x8 __attribute__((ext_vector_type(8)));
typedef float  f32x4  __attribute__((ext_vector_type(4)));

// ---- fp32 -> bf16 (RNE) ----------------------------------------------------
__device__ __forceinline__ uint16_t f2bf(float f) {
  union { float f; uint32_t u; } v; v.f = f;
  uint32_t u = v.u;
  u += 0x7FFFu + ((u >> 16) & 1u);
  return (uint16_t)(u >> 16);
}

__global__ __launch_bounds__(256) void cvt_bf16_kernel(
    const float* __restrict__ x, uint16_t* __restrict__ y, int n) {
  int i = (blockIdx.x * 256 + threadIdx.x) * 4;
  if (i + 3 < n) {
    float4 v = *(const float4*)(x + i);
    ushort4 o;
    o.x = f2bf(v.x); o.y = f2bf(v.y); o.z = f2bf(v.z); o.w = f2bf(v.w);
    *(ushort4*)(y + i) = o;
  }
}

// ---- async global->LDS staging (16B / lane) --------------------------------
#if defined(__has_builtin)
#if __has_builtin(__builtin_amdgcn_global_load_lds)
#define HAVE_GLL 1
#endif
#endif

__device__ __forceinline__ void stage16(const uint16_t* g, uint16_t* lds_wave_base, int lane) {
#ifdef HAVE_GLL
  __builtin_amdgcn_global_load_lds(
      (const __attribute__((address_space(1))) void*)g,
      (__attribute__((address_space(3))) void*)lds_wave_base, 16, 0, 0);
#else
  *(uint4*)(lds_wave_base + lane * 8) = *(const uint4*)g;
#endif
}

// ---- sim = X @ X^T, symmetric-triangle version -----------------------------
// 2D grid 32x32; blocks with bj<bi exit immediately. Diagonal blocks stage
// only A (B fragments read from sA). Off-diagonal blocks mirror-store.
// MFMA value at (r,c) is bit-identical to (c,r) (same products, same k-order)
// so the diagonal tile needs no mirror and overlaps are benign.
__global__ __launch_bounds__(256) void simgemm_kernel(
    const uint16_t* __restrict__ X, float* __restrict__ C, int B, int D) {
  const int bi = blockIdx.x;
  const int bj = blockIdx.y;
  if (bj < bi) return;
  const bool diag = (bi == bj);

  __shared__ __align__(16) uint16_t sA[128 * 32];
  __shared__ __align__(16) uint16_t sB[128 * 32];

  const int tid  = threadIdx.x;
  const int wave = tid >> 6;
  const int lane = tid & 63;
  const int waveM = wave >> 1, waveN = wave & 1;
  const int bm = bi * 128;
  const int bn = bj * 128;

  const int ch0 = tid;
  const int ch1 = tid + 256;
  const int r0 = ch0 >> 2, c0 = (ch0 & 3) * 8;
  const int r1 = ch1 >> 2, c1 = (ch1 & 3) * 8;

  const uint16_t* gA = X + (size_t)bm * D;
  const uint16_t* gB = X + (size_t)bn * D;

  uint16_t* lA0 = sA + wave * 512;
  uint16_t* lA1 = sA + 2048 + wave * 512;
  uint16_t* lB0 = sB + wave * 512;
  uint16_t* lB1 = sB + 2048 + wave * 512;

  const int fr = lane & 15;
  const int fq = lane >> 4;
  const int aoff = (waveM * 64 + fr) * 32 + fq * 8;
  const int boff = (waveN * 64 + fr) * 32 + fq * 8;

  const uint16_t* sBsrc = diag ? sA : sB;

  f32x4 acc[4][4] = {};

  for (int k0 = 0; k0 < D; k0 += 32) {
    stage16(gA + (size_t)r0 * D + k0 + c0, lA0, lane);
    stage16(gA + (size_t)r1 * D + k0 + c1, lA1, lane);
    if (!diag) {
      stage16(gB + (size_t)r0 * D + k0 + c0, lB0, lane);
      stage16(gB + (size_t)r1 * D + k0 + c1, lB1, lane);
    }
    __syncthreads();

    bf16x8 af[4], bfv[4];
#pragma unroll
    for (int t = 0; t < 4; ++t) af[t]  = *(const bf16x8*)(sA + aoff + t * 512);
#pragma unroll
    for (int t = 0; t < 4; ++t) bfv[t] = *(const bf16x8*)(sBsrc + boff + t * 512);

#pragma unroll
    for (int mt = 0; mt < 4; ++mt)
#pragma unroll
      for (int nt = 0; nt < 4; ++nt)
        acc[mt][nt] = __builtin_amdgcn_mfma_f32_16x16x32_bf16(
            af[mt], bfv[nt], acc[mt][nt], 0, 0, 0);
    __syncthreads();
  }

#pragma unroll
  for (int mt = 0; mt < 4; ++mt) {
#pragma unroll
    for (int nt = 0; nt < 4; ++nt) {
      const int col = bn + waveN * 64 + nt * 16 + fr;
#pragma unroll
      for (int r = 0; r < 4; ++r) {
        const int row = bm + waveM * 64 + mt * 16 + fq * 4 + r;
        C[(size_t)row * B + col] = acc[mt][nt][r];
        if (!diag) C[(size_t)col * B + row] = acc[mt][nt][r];
      }
    }
  }
}

// ---- per-row mining + loss -------------------------------------------------
// 4 rows per block (grid B/4 = 1024 -> 4 blocks/CU). Per row: 256 threads x
// 16 elements, sim values + column labels stashed in registers; min/max
// block-reduce; exp-sums computed FROM REGISTERS (sim read once total).
__global__ __launch_bounds__(256) void rowloss_kernel(
    const float* __restrict__ sim, const int* __restrict__ labels,
    float* __restrict__ rowbuf, int B) {
  __shared__ float red[8];

  const int base = blockIdx.x * 4;
  const int tid  = threadIdx.x;
  const int wave = tid >> 6;
  const int lane = tid & 63;

  // this thread's 16 column labels (same for all 4 rows)
  int lab[16];
#pragma unroll
  for (int s = 0; s < 4; ++s) {
    const int j = s * 1024 + tid * 4;
    int4 lv = *(const int4*)(labels + j);
    lab[s * 4 + 0] = lv.x; lab[s * 4 + 1] = lv.y;
    lab[s * 4 + 2] = lv.z; lab[s * 4 + 3] = lv.w;
  }

  for (int r = 0; r < 4; ++r) {
    const int i  = base + r;
    const int li = labels[i];
    const float* row = sim + (size_t)i * B;

    float sv[16];
    unsigned same = 0;   // bit: labels[jj]==li
    unsigned vpos = 0;   // bit: valid positive (same, jj!=i, s<POS_CAP)
    float minpos = __builtin_inff();
    float maxneg = -__builtin_inff();

#pragma unroll
    for (int s = 0; s < 4; ++s) {
      const int j = s * 1024 + tid * 4;
      float4 v = *(const float4*)(row + j);
      float s4[4] = {v.x, v.y, v.z, v.w};
#pragma unroll
      for (int q = 0; q < 4; ++q) {
        const int idx = s * 4 + q;
        const int jj  = j + q;
        const float sij = s4[q];
        sv[idx] = sij;
        if (lab[idx] == li) {
          same |= (1u << idx);
          if (jj != i && sij < POS_CAP) {
            vpos |= (1u << idx);
            minpos = fminf(minpos, sij);
          }
        } else {
          maxneg = fmaxf(maxneg, sij);
        }
      }
    }

#pragma unroll
    for (int m = 32; m > 0; m >>= 1) {
      minpos = fminf(minpos, __shfl_xor(minpos, m, 64));
      maxneg = fmaxf(maxneg, __shfl_xor(maxneg, m, 64));
    }
    if (lane == 0) { red[wave] = minpos; red[4 + wave] = maxneg; }
    __syncthreads();
    minpos = fminf(fminf(red[0], red[1]), fminf(red[2], red[3]));
    maxneg = fmaxf(fmaxf(red[4], red[5]), fmaxf(red[6], red[7]));
    __syncthreads();

    // exp-sums from registers
    float psum = 0.f, nsum = 0.f;
#pragma unroll
    for (int idx = 0; idx < 16; ++idx) {
      const float sij = sv[idx];
      if ((vpos >> idx) & 1u) {
        if (sij - MARGIN < maxneg) psum += __expf(-SCALE_POS * (sij - THRESH));
      } else if (!((same >> idx) & 1u)) {
        if (sij + MARGIN > minpos) nsum += __expf(SCALE_NEG * (sij - THRESH));
      }
    }

#pragma unroll
    for (int m = 32; m > 0; m >>= 1) {
      psum += __shfl_xor(psum, m, 64);
      nsum += __shfl_xor(nsum, m, 64);
    }
    if (lane == 0) { red[wave] = psum; red[4 + wave] = nsum; }
    __syncthreads();

    if (tid == 0) {
      psum = red[0] + red[1] + red[2] + red[3];
      nsum = red[4] + red[5] + red[6] + red[7];
      const bool has_row = (minpos != __builtin_inff()) &&
                           (maxneg != -__builtin_inff()) &&
                           (psum > 0.f) && (nsum > 0.f);
      rowbuf[i] = has_row
          ? (log1pf(psum) * (1.0f / SCALE_POS) + log1pf(nsum) * (1.0f / SCALE_NEG))
          : 0.f;
    }
    __syncthreads();  // red reused next row
  }
}

// ---- final reduction: 4096 floats -> out[0] --------------------------------
__global__ __launch_bounds__(256) void finalreduce_kernel(
    const float* __restrict__ rowbuf, float* __restrict__ out, int B) {
  __shared__ float red[4];
  const int tid  = threadIdx.x;
  const int wave = tid >> 6;
  const int lane = tid & 63;

  float s = 0.f;
  for (int j = tid * 4; j < B; j += 1024) {
    float4 v = *(const float4*)(rowbuf + j);
    s += v.x + v.y + v.z + v.w;
  }
#pragma unroll
  for (int m = 32; m > 0; m >>= 1) s += __shfl_xor(s, m, 64);
  if (lane == 0) red[wave] = s;
  __syncthreads();
  if (tid == 0)
    out[0] = (red[0] + red[1] + red[2] + red[3]) * (1.0f / (float)B);
}

// ---------------------------------------------------------------------------
extern "C" void kernel_launch(void* const* d_in, const int* in_sizes, int n_in,
                              void* d_out, int out_size, void* d_ws, size_t ws_size,
                              hipStream_t stream) {
  const float* x      = (const float*)d_in[0];
  const int*   labels = (const int*)d_in[1];
  float*       out    = (float*)d_out;

  const int B = in_sizes[1];           // 4096
  const int D = in_sizes[0] / B;       // 1024

  uint16_t* xbf = (uint16_t*)d_ws;
  size_t xbytes = (((size_t)B * D * 2) + 255) & ~(size_t)255;
  float* sim = (float*)((char*)d_ws + xbytes);
  size_t simbytes = (size_t)B * B * 4;
  float* rowbuf = (float*)((char*)d_ws + xbytes + simbytes);

  const int n = B * D;
  cvt_bf16_kernel<<<n / 1024, 256, 0, stream>>>(x, xbf, n);

  dim3 grid(B / 128, B / 128);
  simgemm_kernel<<<grid, 256, 0, stream>>>(xbf, sim, B, D);

  rowloss_kernel<<<B / 4, 256, 0, stream>>>(sim, labels, rowbuf, B);
  finalreduce_kernel<<<1, 256, 0, stream>>>(rowbuf, out, B);
}